// Round 19
// baseline (131.868 us; speedup 1.0000x reference)
//
#include <hip/hip_runtime.h>
#include <hip/hip_bf16.h>

#define N_NODES 50000
#define DEG 16
#define NE 800000
#define HID 128
#define NH 32
#define ECH 64
#define NG 64
#define NSLOT 32
#define ITER 4
#define LN_EPS 1e-5f

typedef __bf16 bf16x8 __attribute__((ext_vector_type(8)));
typedef float f32x4 __attribute__((ext_vector_type(4)));

__device__ __forceinline__ unsigned short f2bf(float f) {
  unsigned int u = __float_as_uint(f);
  u += 0x7FFFu + ((u >> 16) & 1u);          // round-to-nearest-even
  return (unsigned short)(u >> 16);
}
__device__ __forceinline__ unsigned int pack2(float a, float b) {
  return (unsigned int)f2bf(a) | ((unsigned int)f2bf(b) << 16);
}

// ---------------------------------------------------------------- prep ------
__global__ void prep_kernel(const float* __restrict__ Wq, const float* __restrict__ Wkv,
                            const float* __restrict__ Wdk,
                            unsigned short* __restrict__ WBf,
                            unsigned short* __restrict__ Wdkf,
                            float* __restrict__ gsum) {
  int b = blockIdx.x, t = threadIdx.x;
  if (b < 16) {
    int n = b;
    for (int idx = t; idx < 2048; idx += 256) {
      int j = idx & 7, l = (idx >> 3) & 63, kk = idx >> 9;
      int col = n * 16 + (l & 15);
      int k = kk * 32 + (l >> 4) * 8 + j;
      float v = (col < HID) ? Wq[k * HID + col] : Wkv[k * HID + (col - HID)];
      WBf[((n * 4 + kk) * 64 + l) * 8 + j] = f2bf(v);
    }
  } else if (b < 24) {
    int n2 = b - 16;
    for (int idx = t; idx < 1024; idx += 256) {
      int j = idx & 7, l = (idx >> 3) & 63, kk = idx >> 9;
      int col = n2 * 16 + (l & 15);
      int k = kk * 32 + (l >> 4) * 8 + j;
      Wdkf[((n2 * 2 + kk) * 64 + l) * 8 + j] = f2bf(Wdk[k * HID + col]);
    }
  } else {
    int chunk = b - 24;                      // 8 blocks zero NG*NSLOT*HID floats
    const int tot = NG * NSLOT * HID / 8;    // 32768 per block
    for (int i = chunk * tot + t; i < (chunk + 1) * tot; i += 256)
      gsum[i] = 0.0f;
  }
}

// ------------------------------------------------------------- node pass ----
__global__ __launch_bounds__(256) void node_kernel(
    const float* __restrict__ x, const float* __restrict__ bq,
    const float* __restrict__ bkv, const float* __restrict__ lng,
    const float* __restrict__ lnb, const unsigned short* __restrict__ WBf,
    unsigned short* __restrict__ qout, unsigned short* __restrict__ kout) {
  __shared__ __align__(16) unsigned short xn[64 * HID];
  int t = threadIdx.x;
  int node0 = blockIdx.x * 64;
  {
    int row = t >> 2, q4 = t & 3;
    int c0 = q4 * 32;
    int node = node0 + row;
    float v[32];
    if (node < N_NODES) {
      const float4* xp = (const float4*)(x + node * HID + c0);
#pragma unroll
      for (int i = 0; i < 8; i++) {
        float4 f = xp[i];
        v[4 * i] = f.x; v[4 * i + 1] = f.y; v[4 * i + 2] = f.z; v[4 * i + 3] = f.w;
      }
    } else {
#pragma unroll
      for (int i = 0; i < 32; i++) v[i] = 0.f;
    }
    float s = 0.f;
#pragma unroll
    for (int i = 0; i < 32; i++) s += v[i];
    s += __shfl_xor(s, 1); s += __shfl_xor(s, 2);
    float m = s * (1.0f / HID);
    float sq = 0.f;
#pragma unroll
    for (int i = 0; i < 32; i++) { float d = v[i] - m; sq += d * d; }
    sq += __shfl_xor(sq, 1); sq += __shfl_xor(sq, 2);
    float rstd = rsqrtf(sq * (1.0f / HID) + LN_EPS);
#pragma unroll
    for (int ch = 0; ch < 4; ch++) {
      float w0[8];
#pragma unroll
      for (int j = 0; j < 8; j++) {
        int c = c0 + ch * 8 + j;
        w0[j] = (v[ch * 8 + j] - m) * rstd * lng[c] + lnb[c];
      }
      uint4 u;
      u.x = pack2(w0[0], w0[1]); u.y = pack2(w0[2], w0[3]);
      u.z = pack2(w0[4], w0[5]); u.w = pack2(w0[6], w0[7]);
      int byte = row * 256 + ((c0 * 2 + ch * 16) ^ ((row & 7) << 4));
      *(uint4*)((char*)xn + byte) = u;
    }
  }
  __syncthreads();
  int w = t >> 6, l = t & 63;
  int arow = w * 16 + (l & 15);
  bf16x8 a[4];
#pragma unroll
  for (int kk = 0; kk < 4; kk++) {
    int byte = arow * 256 + ((kk * 64 + (l >> 4) * 16) ^ ((arow & 7) << 4));
    a[kk] = *(const bf16x8*)((const char*)xn + byte);
  }
  f32x4 acc[16];
#pragma unroll
  for (int n = 0; n < 16; n++) acc[n] = (f32x4){0.f, 0.f, 0.f, 0.f};
#pragma unroll
  for (int n = 0; n < 16; n++)
#pragma unroll
    for (int kk = 0; kk < 4; kk++) {
      bf16x8 bfr = *(const bf16x8*)(WBf + ((n * 4 + kk) * 64 + l) * 8);
      acc[n] = __builtin_amdgcn_mfma_f32_16x16x32_bf16(a[kk], bfr, acc[n], 0, 0, 0);
    }
#pragma unroll
  for (int n = 0; n < 16; n++) {
    int col = n * 16 + (l & 15);
    float bias = (col < HID) ? bq[col] : bkv[col - HID];
#pragma unroll
    for (int r = 0; r < 4; r++) {
      int node = node0 + w * 16 + (l >> 4) * 4 + r;
      if (node < N_NODES) {
        float vv = acc[n][r] + bias;
        if (col < HID) qout[node * HID + col] = f2bf(vv);
        else kout[node * HID + (col - HID)] = f2bf(vv);
      }
    }
  }
}

// ------------------------------------------------------------- edge pass ----
// R15 wave-private pipeline, but the main loop is a RUNTIME loop over pairs
// (2 inlined bodies with literal slot index) instead of a full ITER unroll:
// code size ~2 bodies (~24 KB) stays I$-resident vs 5 bodies (~60 KB)
// streaming from L2 every iteration. Prefetch conditionals replaced by
// clamped indices (last-pair loads redundant but cache-hot and valid).
__global__ __launch_bounds__(256, 2) void edge_kernel(
    const float* __restrict__ x, const float* __restrict__ ea,
    const int* __restrict__ src_arr, const int* __restrict__ batch,
    const float* __restrict__ bdk, const float* __restrict__ lng,
    const float* __restrict__ lnb, const unsigned short* __restrict__ qbf,
    const unsigned short* __restrict__ kbf,
    const unsigned short* __restrict__ Wdkf, float* __restrict__ gsum) {
  __shared__ __align__(16) unsigned short wdk_s[8 * 2 * 64 * 8];  // 16 KB
  __shared__ __align__(16) float bdk_s[HID];                      // 0.5 KB
  __shared__ __align__(16) unsigned short k_s[4][2048];           // 16 KB
  __shared__ __align__(16) unsigned int q_s[4][64];               // 1 KB
  __shared__ __align__(16) float at_s[4][16 * 33];                // 8.4 KB
  int t = threadIdx.x, w = t >> 6, l = t & 63, el = l & 15, eh = l >> 4;
  int g0 = blockIdx.x * ITER;
  int slot = (blockIdx.x * 4 + w) & (NSLOT - 1);
  char* ksw = (char*)&k_s[w][0];
  unsigned int* qsw = &q_s[w][0];
  float* atw = &at_s[w][0];

  if (t < HID) bdk_s[t] = bdk[t];
#pragma unroll
  for (int i = 0; i < 4; i++) {
    int idx = (i * 256 + t) * 8;
    *(uint4*)(wdk_s + idx) = *(const uint4*)(Wdkf + idx);
  }
  // loop-invariant channel-major LN params (registers)
  float2 gv = *(const float2*)(lng + 2 * l);
  float2 bv = *(const float2*)(lnb + 2 * l);

  // per-wave aggregation state
  int curG = batch[g0 * 4 + w];
  float accu0 = 0.f, accu1 = 0.f;

  // ping-pong register slots
  unsigned int kwR[2][16];
  f32x4 eaR[2][4];
  float2 xR[2];
  unsigned int qR[2];
  int srcR[2], bR[2];

  auto LOAD_SRC = [&](int i) -> int {
    return src_arr[((size_t)(g0 + i) * 4 + w) * DEG + el];
  };
  auto LOAD_NODE = [&](int i, int s) {
    size_t node = (size_t)(g0 + i) * 4 + w;
    const float* p = ea + (node * DEG + el) * ECH + eh * 8;
    eaR[s][0] = __builtin_nontemporal_load((const f32x4*)p);
    eaR[s][1] = __builtin_nontemporal_load((const f32x4*)(p + 4));
    eaR[s][2] = __builtin_nontemporal_load((const f32x4*)(p + 32));
    eaR[s][3] = __builtin_nontemporal_load((const f32x4*)(p + 36));
    xR[s] = *(const float2*)(x + node * HID + 2 * l);
    qR[s] = *(const unsigned int*)(qbf + node * HID + 2 * l);
    bR[s] = batch[node];
  };
  auto GATHER = [&](int s) {
    int sv = srcR[s];
#pragma unroll
    for (int e = 0; e < 16; e++) {
      int sw = __shfl(sv, e, 16);
      kwR[s][e] = *(const unsigned int*)(kbf + (size_t)sw * HID + 2 * l);
    }
  };

  // one loop body; cur/nxt are LITERAL arguments -> compile-time indexing
  auto BODY = [&](int i, int cur, int nxt) __attribute__((always_inline)) {
    // ---- issue next-node memory ops (clamped; redundant on last pair) -----
    GATHER(nxt);
    int ip2 = (i + 2 < ITER) ? i + 2 : ITER - 1;
    srcR[cur] = LOAD_SRC(ip2);
    int ip1 = (i + 1 < ITER) ? i + 1 : ITER - 1;
    LOAD_NODE(ip1, nxt);
    // ---- wave-private staging (same-wave write->read, no barrier) ---------
#pragma unroll
    for (int e = 0; e < 16; e++)
      *(unsigned int*)(ksw + e * 256 + ((4 * l) ^ ((e & 7) << 4))) = kwR[cur][e];
    qsw[l] = qR[cur];
    // ---- convert ea -> bf16 fragments -------------------------------------
    bf16x8 bfr[2];
#pragma unroll
    for (int kk = 0; kk < 2; kk++)
#pragma unroll
      for (int j = 0; j < 4; j++) {
        bfr[kk][j]     = (__bf16)eaR[cur][kk * 2][j];
        bfr[kk][4 + j] = (__bf16)eaR[cur][kk * 2 + 1][j];
      }
    float2 xv = xR[cur];
    int b_cur = bR[cur];
    // ---- dk^T MFMA --------------------------------------------------------
    f32x4 acc[8];
#pragma unroll
    for (int n = 0; n < 8; n++) acc[n] = (f32x4){0.f, 0.f, 0.f, 0.f};
#pragma unroll
    for (int n = 0; n < 8; n++)
#pragma unroll
      for (int kk = 0; kk < 2; kk++) {
        bf16x8 af = *(const bf16x8*)(wdk_s + ((n * 2 + kk) * 64 + l) * 8);
        acc[n] = __builtin_amdgcn_mfma_f32_16x16x32_bf16(af, bfr[kk], acc[n], 0, 0, 0);
      }
    // ---- phase 1: attention logits + silu (edge-major) --------------------
#pragma unroll
    for (int n = 0; n < 8; n++) {
      const int cb = n * 16 + eh * 4;
      uint2 qu = *(const uint2*)&qsw[n * 8 + eh * 2];
      float q0 = __uint_as_float(qu.x << 16);
      float q1 = __uint_as_float(qu.x & 0xFFFF0000u);
      float q2 = __uint_as_float(qu.y << 16);
      float q3 = __uint_as_float(qu.y & 0xFFFF0000u);
      f32x4 bd = *(const f32x4*)&bdk_s[cb];
      uint2 kk2 = *(const uint2*)(ksw + el * 256 + ((n * 32 + eh * 8) ^ ((el & 7) << 4)));
      float k0 = __uint_as_float(kk2.x << 16);
      float k1 = __uint_as_float(kk2.x & 0xFFFF0000u);
      float k2 = __uint_as_float(kk2.y << 16);
      float k3 = __uint_as_float(kk2.y & 0xFFFF0000u);
      float d0 = acc[n][0] + bd[0];
      float d1 = acc[n][1] + bd[1];
      float d2 = acc[n][2] + bd[2];
      float d3 = acc[n][3] + bd[3];
      float s = q0 * k0 * d0 + q1 * k1 * d1 + q2 * k2 * d2 + q3 * k3 * d3;
      float at = s * __builtin_amdgcn_rcpf(1.0f + __expf(-s));   // silu
      atw[el * 33 + n * 4 + eh] = at;                            // same-wave
    }
    // ---- phase 2: channel-major message accumulation (kw from regs) -------
    int hl = l >> 1;
    float macc0 = 0.f, macc1 = 0.f;
#pragma unroll
    for (int e = 0; e < 16; e++) {
      float at = atw[e * 33 + hl];
      macc0 = fmaf(__uint_as_float(kwR[cur][e] << 16), at, macc0);
      macc1 = fmaf(__uint_as_float(kwR[cur][e] & 0xFFFF0000u), at, macc1);
    }
    float h10 = xv.x + macc0 * 0.0625f;
    float h11 = xv.y + macc1 * 0.0625f;
    // ---- LayerNorm (64-lane reduce) ---------------------------------------
    float ss = h10 + h11;
    ss += __shfl_xor(ss, 1);  ss += __shfl_xor(ss, 2);  ss += __shfl_xor(ss, 4);
    ss += __shfl_xor(ss, 8);  ss += __shfl_xor(ss, 16); ss += __shfl_xor(ss, 32);
    float mean = ss * (1.0f / HID);
    float dv0 = h10 - mean, dv1 = h11 - mean;
    float vv = dv0 * dv0 + dv1 * dv1;
    vv += __shfl_xor(vv, 1);  vv += __shfl_xor(vv, 2);  vv += __shfl_xor(vv, 4);
    vv += __shfl_xor(vv, 8);  vv += __shfl_xor(vv, 16); vv += __shfl_xor(vv, 32);
    float rstd = rsqrtf(vv * (1.0f / HID) + LN_EPS);
    float ho0 = xv.x + dv0 * rstd * gv.x + bv.x;
    float ho1 = xv.y + dv1 * rstd * gv.y + bv.y;
    // ---- per-wave run-length aggregation ----------------------------------
    if (b_cur != curG) {
      atomicAdd(&gsum[(curG * NSLOT + slot) * HID + 2 * l], accu0);
      atomicAdd(&gsum[(curG * NSLOT + slot) * HID + 2 * l + 1], accu1);
      accu0 = 0.f; accu1 = 0.f; curG = b_cur;
    }
    accu0 += ho0; accu1 += ho1;
  };

  // prologue
  srcR[0] = LOAD_SRC(0);
  LOAD_NODE(0, 0);
  srcR[1] = LOAD_SRC(1);
  GATHER(0);

  __syncthreads();                           // wdk_s / bdk_s ready (only barrier)

  // runtime loop over pairs: exactly 2 body copies in the binary
#pragma unroll 1
  for (int ii = 0; ii < ITER; ii += 2) {
    BODY(ii, 0, 1);
    BODY(ii + 1, 1, 0);
  }
  atomicAdd(&gsum[(curG * NSLOT + slot) * HID + 2 * l], accu0);
  atomicAdd(&gsum[(curG * NSLOT + slot) * HID + 2 * l + 1], accu1);
}

// -------------------------------------------------------------- readout -----
__global__ void readout_kernel(const float* __restrict__ gsum,
                               const int* __restrict__ batch,
                               const float* __restrict__ Wout,
                               const float* __restrict__ bout,
                               float* __restrict__ out) {
  int g = blockIdx.x, l = threadIdx.x;
  int lo = 0, hi = N_NODES;
  while (lo < hi) { int mid = (lo + hi) >> 1; if (batch[mid] < g) lo = mid + 1; else hi = mid; }
  int lo2 = lo, hi2 = N_NODES;
  while (lo2 < hi2) { int mid = (lo2 + hi2) >> 1; if (batch[mid] < g + 1) lo2 = mid + 1; else hi2 = mid; }
  int cnt = lo2 - lo; if (cnt < 1) cnt = 1;
  float a0 = 0.f, a1 = 0.f;
#pragma unroll 4
  for (int s = 0; s < NSLOT; s++) {
    const float* row = gsum + ((size_t)g * NSLOT + s) * HID;
    a0 += row[l];
    a1 += row[64 + l];
  }
  float v = a0 * Wout[l] + a1 * Wout[64 + l];
#pragma unroll
  for (int s = 32; s >= 1; s >>= 1) v += __shfl_xor(v, s);
  if (l == 0) out[g] = v / (float)cnt + bout[0];
}

// ---------------------------------------------------------------------------
extern "C" void kernel_launch(void* const* d_in, const int* in_sizes, int n_in,
                              void* d_out, int out_size, void* d_ws, size_t ws_size,
                              hipStream_t stream) {
  const float* x         = (const float*)d_in[0];
  const float* edge_attr = (const float*)d_in[1];
  const float* Wq        = (const float*)d_in[2];
  const float* bq        = (const float*)d_in[3];
  const float* Wkv       = (const float*)d_in[4];
  const float* bkv       = (const float*)d_in[5];
  const float* Wdk       = (const float*)d_in[6];
  const float* bdk       = (const float*)d_in[7];
  const float* ln_in_g   = (const float*)d_in[8];
  const float* ln_in_b   = (const float*)d_in[9];
  const float* ln_out_g  = (const float*)d_in[10];
  const float* ln_out_b  = (const float*)d_in[11];
  const float* Wout      = (const float*)d_in[12];
  const float* bout      = (const float*)d_in[13];
  const int* edge_index  = (const int*)d_in[14];   // [2][E]: src then dst
  const int* batch       = (const int*)d_in[15];
  float* outp = (float*)d_out;

  char* ws = (char*)d_ws;
  unsigned short* qbuf = (unsigned short*)ws;                          // 12.8 MB
  unsigned short* kbuf = (unsigned short*)(ws + 12800000);             // 12.8 MB
  unsigned short* WBf  = (unsigned short*)(ws + 25600000);             // 64 KB
  unsigned short* Wdkf = (unsigned short*)(ws + 25600000 + 65536);     // 16 KB
  float* gsum          = (float*)(ws + 25600000 + 65536 + 16384);      // 1 MB

  prep_kernel<<<32, 256, 0, stream>>>(Wq, Wkv, Wdk, WBf, Wdkf, gsum);
  node_kernel<<<(N_NODES + 63) / 64, 256, 0, stream>>>(x, bq, bkv, ln_in_g, ln_in_b,
                                                       WBf, qbuf, kbuf);
  edge_kernel<<<N_NODES / (4 * ITER), 256, 0, stream>>>(x, edge_attr, edge_index, batch,
                                                        bdk, ln_out_g, ln_out_b, qbuf,
                                                        kbuf, Wdkf, gsum);
  readout_kernel<<<NG, 64, 0, stream>>>(gsum, batch, Wout, bout, outp);
}

// Round 20
// 122.497 us; speedup vs baseline: 1.0765x; 1.0765x over previous
//
#include <hip/hip_runtime.h>
#include <hip/hip_bf16.h>

#define N_NODES 50000
#define DEG 16
#define NE 800000
#define HID 128
#define NH 32
#define ECH 64
#define NG 64
#define NSLOT 32
#define ITER 5
#define LN_EPS 1e-5f

typedef __bf16 bf16x8 __attribute__((ext_vector_type(8)));
typedef float f32x4 __attribute__((ext_vector_type(4)));

__device__ __forceinline__ unsigned short f2bf(float f) {
  unsigned int u = __float_as_uint(f);
  u += 0x7FFFu + ((u >> 16) & 1u);          // round-to-nearest-even
  return (unsigned short)(u >> 16);
}
__device__ __forceinline__ unsigned int pack2(float a, float b) {
  return (unsigned int)f2bf(a) | ((unsigned int)f2bf(b) << 16);
}

// ---------------------------------------------------------------- prep ------
__global__ void prep_kernel(const float* __restrict__ Wq, const float* __restrict__ Wkv,
                            const float* __restrict__ Wdk,
                            unsigned short* __restrict__ WBf,
                            unsigned short* __restrict__ Wdkf,
                            float* __restrict__ gsum) {
  int b = blockIdx.x, t = threadIdx.x;
  if (b < 16) {
    int n = b;
    for (int idx = t; idx < 2048; idx += 256) {
      int j = idx & 7, l = (idx >> 3) & 63, kk = idx >> 9;
      int col = n * 16 + (l & 15);
      int k = kk * 32 + (l >> 4) * 8 + j;
      float v = (col < HID) ? Wq[k * HID + col] : Wkv[k * HID + (col - HID)];
      WBf[((n * 4 + kk) * 64 + l) * 8 + j] = f2bf(v);
    }
  } else if (b < 24) {
    int n2 = b - 16;
    for (int idx = t; idx < 1024; idx += 256) {
      int j = idx & 7, l = (idx >> 3) & 63, kk = idx >> 9;
      int col = n2 * 16 + (l & 15);
      int k = kk * 32 + (l >> 4) * 8 + j;
      Wdkf[((n2 * 2 + kk) * 64 + l) * 8 + j] = f2bf(Wdk[k * HID + col]);
    }
  } else {
    int chunk = b - 24;                      // 8 blocks zero NG*NSLOT*HID floats
    const int tot = NG * NSLOT * HID / 8;    // 32768 per block
    for (int i = chunk * tot + t; i < (chunk + 1) * tot; i += 256)
      gsum[i] = 0.0f;
  }
}

// ------------------------------------------------------------- node pass ----
__global__ __launch_bounds__(256) void node_kernel(
    const float* __restrict__ x, const float* __restrict__ bq,
    const float* __restrict__ bkv, const float* __restrict__ lng,
    const float* __restrict__ lnb, const unsigned short* __restrict__ WBf,
    unsigned short* __restrict__ qout, unsigned short* __restrict__ kout) {
  __shared__ __align__(16) unsigned short xn[64 * HID];
  int t = threadIdx.x;
  int node0 = blockIdx.x * 64;
  {
    int row = t >> 2, q4 = t & 3;
    int c0 = q4 * 32;
    int node = node0 + row;
    float v[32];
    if (node < N_NODES) {
      const float4* xp = (const float4*)(x + node * HID + c0);
#pragma unroll
      for (int i = 0; i < 8; i++) {
        float4 f = xp[i];
        v[4 * i] = f.x; v[4 * i + 1] = f.y; v[4 * i + 2] = f.z; v[4 * i + 3] = f.w;
      }
    } else {
#pragma unroll
      for (int i = 0; i < 32; i++) v[i] = 0.f;
    }
    float s = 0.f;
#pragma unroll
    for (int i = 0; i < 32; i++) s += v[i];
    s += __shfl_xor(s, 1); s += __shfl_xor(s, 2);
    float m = s * (1.0f / HID);
    float sq = 0.f;
#pragma unroll
    for (int i = 0; i < 32; i++) { float d = v[i] - m; sq += d * d; }
    sq += __shfl_xor(sq, 1); sq += __shfl_xor(sq, 2);
    float rstd = rsqrtf(sq * (1.0f / HID) + LN_EPS);
#pragma unroll
    for (int ch = 0; ch < 4; ch++) {
      float w0[8];
#pragma unroll
      for (int j = 0; j < 8; j++) {
        int c = c0 + ch * 8 + j;
        w0[j] = (v[ch * 8 + j] - m) * rstd * lng[c] + lnb[c];
      }
      uint4 u;
      u.x = pack2(w0[0], w0[1]); u.y = pack2(w0[2], w0[3]);
      u.z = pack2(w0[4], w0[5]); u.w = pack2(w0[6], w0[7]);
      int byte = row * 256 + ((c0 * 2 + ch * 16) ^ ((row & 7) << 4));
      *(uint4*)((char*)xn + byte) = u;
    }
  }
  __syncthreads();
  int w = t >> 6, l = t & 63;
  int arow = w * 16 + (l & 15);
  bf16x8 a[4];
#pragma unroll
  for (int kk = 0; kk < 4; kk++) {
    int byte = arow * 256 + ((kk * 64 + (l >> 4) * 16) ^ ((arow & 7) << 4));
    a[kk] = *(const bf16x8*)((const char*)xn + byte);
  }
  f32x4 acc[16];
#pragma unroll
  for (int n = 0; n < 16; n++) acc[n] = (f32x4){0.f, 0.f, 0.f, 0.f};
#pragma unroll
  for (int n = 0; n < 16; n++)
#pragma unroll
    for (int kk = 0; kk < 4; kk++) {
      bf16x8 bfr = *(const bf16x8*)(WBf + ((n * 4 + kk) * 64 + l) * 8);
      acc[n] = __builtin_amdgcn_mfma_f32_16x16x32_bf16(a[kk], bfr, acc[n], 0, 0, 0);
    }
#pragma unroll
  for (int n = 0; n < 16; n++) {
    int col = n * 16 + (l & 15);
    float bias = (col < HID) ? bq[col] : bkv[col - HID];
#pragma unroll
    for (int r = 0; r < 4; r++) {
      int node = node0 + w * 16 + (l >> 4) * 4 + r;
      if (node < N_NODES) {
        float vv = acc[n][r] + bias;
        if (col < HID) qout[node * HID + col] = f2bf(vv);
        else kout[node * HID + (col - HID)] = f2bf(vv);
      }
    }
  }
}

// ------------------------------------------------------------- edge pass ----
// Wave-private pipeline (session best, 123.2 µs): block = 4 independent
// waves; wave w handles nodes (g0+i)*4+w (increasing over sorted batch).
// ZERO per-iteration barriers: x read channel-major into registers; q staged
// wave-private; k_s/at_s wave-private; per-wave register run-length
// aggregation. wdk_s/bdk_s staged once (single barrier at start).
__global__ __launch_bounds__(256, 2) void edge_kernel(
    const float* __restrict__ x, const float* __restrict__ ea,
    const int* __restrict__ src_arr, const int* __restrict__ batch,
    const float* __restrict__ bdk, const float* __restrict__ lng,
    const float* __restrict__ lnb, const unsigned short* __restrict__ qbf,
    const unsigned short* __restrict__ kbf,
    const unsigned short* __restrict__ Wdkf, float* __restrict__ gsum) {
  __shared__ __align__(16) unsigned short wdk_s[8 * 2 * 64 * 8];  // 16 KB
  __shared__ __align__(16) float bdk_s[HID];                      // 0.5 KB
  __shared__ __align__(16) unsigned short k_s[4][2048];           // 16 KB
  __shared__ __align__(16) unsigned int q_s[4][64];               // 1 KB
  __shared__ __align__(16) float at_s[4][16 * 33];                // 8.4 KB
  int t = threadIdx.x, w = t >> 6, l = t & 63, el = l & 15, eh = l >> 4;
  int g0 = blockIdx.x * ITER;
  int slot = (blockIdx.x * 4 + w) & (NSLOT - 1);
  char* ksw = (char*)&k_s[w][0];
  unsigned int* qsw = &q_s[w][0];
  float* atw = &at_s[w][0];

  if (t < HID) bdk_s[t] = bdk[t];
#pragma unroll
  for (int i = 0; i < 4; i++) {
    int idx = (i * 256 + t) * 8;
    *(uint4*)(wdk_s + idx) = *(const uint4*)(Wdkf + idx);
  }
  // loop-invariant channel-major LN params (registers)
  float2 gv = *(const float2*)(lng + 2 * l);
  float2 bv = *(const float2*)(lnb + 2 * l);

  // per-wave aggregation state
  int curG = batch[g0 * 4 + w];
  float accu0 = 0.f, accu1 = 0.f;

  // ping-pong register slots
  unsigned int kwR[2][16];
  f32x4 eaR[2][4];
  float2 xR[2];
  unsigned int qR[2];
  int srcR[2], bR[2];

  auto LOAD_SRC = [&](int i) -> int {
    return src_arr[((size_t)(g0 + i) * 4 + w) * DEG + el];
  };
  auto LOAD_NODE = [&](int i, int s) {
    size_t node = (size_t)(g0 + i) * 4 + w;
    const float* p = ea + (node * DEG + el) * ECH + eh * 8;
    eaR[s][0] = __builtin_nontemporal_load((const f32x4*)p);
    eaR[s][1] = __builtin_nontemporal_load((const f32x4*)(p + 4));
    eaR[s][2] = __builtin_nontemporal_load((const f32x4*)(p + 32));
    eaR[s][3] = __builtin_nontemporal_load((const f32x4*)(p + 36));
    xR[s] = *(const float2*)(x + node * HID + 2 * l);
    qR[s] = *(const unsigned int*)(qbf + node * HID + 2 * l);
    bR[s] = batch[node];
  };
  auto GATHER = [&](int s) {
    int sv = srcR[s];
#pragma unroll
    for (int e = 0; e < 16; e++) {
      int sw = __shfl(sv, e, 16);
      kwR[s][e] = *(const unsigned int*)(kbf + (size_t)sw * HID + 2 * l);
    }
  };

  // prologue
  srcR[0] = LOAD_SRC(0);
  LOAD_NODE(0, 0);
  srcR[1] = (ITER > 1) ? LOAD_SRC(1) : 0;
  GATHER(0);

  __syncthreads();                           // wdk_s / bdk_s ready (only barrier)

#pragma unroll
  for (int i = 0; i < ITER; i++) {
    const int cur = i & 1, nxt = cur ^ 1;
    // ---- issue next-node memory ops ---------------------------------------
    if (i + 1 < ITER) GATHER(nxt);
    if (i + 2 < ITER) srcR[cur] = LOAD_SRC(i + 2);
    if (i + 1 < ITER) LOAD_NODE(i + 1, nxt);
    // ---- wave-private staging (same-wave write->read, no barrier) ---------
#pragma unroll
    for (int e = 0; e < 16; e++)
      *(unsigned int*)(ksw + e * 256 + ((4 * l) ^ ((e & 7) << 4))) = kwR[cur][e];
    qsw[l] = qR[cur];
    // ---- convert ea -> bf16 fragments -------------------------------------
    bf16x8 bfr[2];
#pragma unroll
    for (int kk = 0; kk < 2; kk++)
#pragma unroll
      for (int j = 0; j < 4; j++) {
        bfr[kk][j]     = (__bf16)eaR[cur][kk * 2][j];
        bfr[kk][4 + j] = (__bf16)eaR[cur][kk * 2 + 1][j];
      }
    float2 xv = xR[cur];
    int b_cur = bR[cur];
    // ---- dk^T MFMA --------------------------------------------------------
    f32x4 acc[8];
#pragma unroll
    for (int n = 0; n < 8; n++) acc[n] = (f32x4){0.f, 0.f, 0.f, 0.f};
#pragma unroll
    for (int n = 0; n < 8; n++)
#pragma unroll
      for (int kk = 0; kk < 2; kk++) {
        bf16x8 af = *(const bf16x8*)(wdk_s + ((n * 2 + kk) * 64 + l) * 8);
        acc[n] = __builtin_amdgcn_mfma_f32_16x16x32_bf16(af, bfr[kk], acc[n], 0, 0, 0);
      }
    // ---- phase 1: attention logits + silu (edge-major) --------------------
#pragma unroll
    for (int n = 0; n < 8; n++) {
      const int cb = n * 16 + eh * 4;
      uint2 qu = *(const uint2*)&qsw[n * 8 + eh * 2];
      float q0 = __uint_as_float(qu.x << 16);
      float q1 = __uint_as_float(qu.x & 0xFFFF0000u);
      float q2 = __uint_as_float(qu.y << 16);
      float q3 = __uint_as_float(qu.y & 0xFFFF0000u);
      f32x4 bd = *(const f32x4*)&bdk_s[cb];
      uint2 kk2 = *(const uint2*)(ksw + el * 256 + ((n * 32 + eh * 8) ^ ((el & 7) << 4)));
      float k0 = __uint_as_float(kk2.x << 16);
      float k1 = __uint_as_float(kk2.x & 0xFFFF0000u);
      float k2 = __uint_as_float(kk2.y << 16);
      float k3 = __uint_as_float(kk2.y & 0xFFFF0000u);
      float d0 = acc[n][0] + bd[0];
      float d1 = acc[n][1] + bd[1];
      float d2 = acc[n][2] + bd[2];
      float d3 = acc[n][3] + bd[3];
      float s = q0 * k0 * d0 + q1 * k1 * d1 + q2 * k2 * d2 + q3 * k3 * d3;
      float at = s * __builtin_amdgcn_rcpf(1.0f + __expf(-s));   // silu
      atw[el * 33 + n * 4 + eh] = at;                            // same-wave
    }
    // ---- phase 2: channel-major message accumulation (kw from regs) -------
    int hl = l >> 1;
    float macc0 = 0.f, macc1 = 0.f;
#pragma unroll
    for (int e = 0; e < 16; e++) {
      float at = atw[e * 33 + hl];
      macc0 = fmaf(__uint_as_float(kwR[cur][e] << 16), at, macc0);
      macc1 = fmaf(__uint_as_float(kwR[cur][e] & 0xFFFF0000u), at, macc1);
    }
    float h10 = xv.x + macc0 * 0.0625f;
    float h11 = xv.y + macc1 * 0.0625f;
    // ---- LayerNorm (64-lane reduce) ---------------------------------------
    float ss = h10 + h11;
    ss += __shfl_xor(ss, 1);  ss += __shfl_xor(ss, 2);  ss += __shfl_xor(ss, 4);
    ss += __shfl_xor(ss, 8);  ss += __shfl_xor(ss, 16); ss += __shfl_xor(ss, 32);
    float mean = ss * (1.0f / HID);
    float dv0 = h10 - mean, dv1 = h11 - mean;
    float vv = dv0 * dv0 + dv1 * dv1;
    vv += __shfl_xor(vv, 1);  vv += __shfl_xor(vv, 2);  vv += __shfl_xor(vv, 4);
    vv += __shfl_xor(vv, 8);  vv += __shfl_xor(vv, 16); vv += __shfl_xor(vv, 32);
    float rstd = rsqrtf(vv * (1.0f / HID) + LN_EPS);
    float ho0 = xv.x + dv0 * rstd * gv.x + bv.x;
    float ho1 = xv.y + dv1 * rstd * gv.y + bv.y;
    // ---- per-wave run-length aggregation ----------------------------------
    if (b_cur != curG) {
      atomicAdd(&gsum[(curG * NSLOT + slot) * HID + 2 * l], accu0);
      atomicAdd(&gsum[(curG * NSLOT + slot) * HID + 2 * l + 1], accu1);
      accu0 = 0.f; accu1 = 0.f; curG = b_cur;
    }
    accu0 += ho0; accu1 += ho1;
  }
  atomicAdd(&gsum[(curG * NSLOT + slot) * HID + 2 * l], accu0);
  atomicAdd(&gsum[(curG * NSLOT + slot) * HID + 2 * l + 1], accu1);
}

// -------------------------------------------------------------- readout -----
__global__ void readout_kernel(const float* __restrict__ gsum,
                               const int* __restrict__ batch,
                               const float* __restrict__ Wout,
                               const float* __restrict__ bout,
                               float* __restrict__ out) {
  int g = blockIdx.x, l = threadIdx.x;
  int lo = 0, hi = N_NODES;
  while (lo < hi) { int mid = (lo + hi) >> 1; if (batch[mid] < g) lo = mid + 1; else hi = mid; }
  int lo2 = lo, hi2 = N_NODES;
  while (lo2 < hi2) { int mid = (lo2 + hi2) >> 1; if (batch[mid] < g + 1) lo2 = mid + 1; else hi2 = mid; }
  int cnt = lo2 - lo; if (cnt < 1) cnt = 1;
  float a0 = 0.f, a1 = 0.f;
#pragma unroll 4
  for (int s = 0; s < NSLOT; s++) {
    const float* row = gsum + ((size_t)g * NSLOT + s) * HID;
    a0 += row[l];
    a1 += row[64 + l];
  }
  float v = a0 * Wout[l] + a1 * Wout[64 + l];
#pragma unroll
  for (int s = 32; s >= 1; s >>= 1) v += __shfl_xor(v, s);
  if (l == 0) out[g] = v / (float)cnt + bout[0];
}

// ---------------------------------------------------------------------------
extern "C" void kernel_launch(void* const* d_in, const int* in_sizes, int n_in,
                              void* d_out, int out_size, void* d_ws, size_t ws_size,
                              hipStream_t stream) {
  const float* x         = (const float*)d_in[0];
  const float* edge_attr = (const float*)d_in[1];
  const float* Wq        = (const float*)d_in[2];
  const float* bq        = (const float*)d_in[3];
  const float* Wkv       = (const float*)d_in[4];
  const float* bkv       = (const float*)d_in[5];
  const float* Wdk       = (const float*)d_in[6];
  const float* bdk       = (const float*)d_in[7];
  const float* ln_in_g   = (const float*)d_in[8];
  const float* ln_in_b   = (const float*)d_in[9];
  const float* ln_out_g  = (const float*)d_in[10];
  const float* ln_out_b  = (const float*)d_in[11];
  const float* Wout      = (const float*)d_in[12];
  const float* bout      = (const float*)d_in[13];
  const int* edge_index  = (const int*)d_in[14];   // [2][E]: src then dst
  const int* batch       = (const int*)d_in[15];
  float* outp = (float*)d_out;

  char* ws = (char*)d_ws;
  unsigned short* qbuf = (unsigned short*)ws;                          // 12.8 MB
  unsigned short* kbuf = (unsigned short*)(ws + 12800000);             // 12.8 MB
  unsigned short* WBf  = (unsigned short*)(ws + 25600000);             // 64 KB
  unsigned short* Wdkf = (unsigned short*)(ws + 25600000 + 65536);     // 16 KB
  float* gsum          = (float*)(ws + 25600000 + 65536 + 16384);      // 1 MB

  prep_kernel<<<32, 256, 0, stream>>>(Wq, Wkv, Wdk, WBf, Wdkf, gsum);
  node_kernel<<<(N_NODES + 63) / 64, 256, 0, stream>>>(x, bq, bkv, ln_in_g, ln_in_b,
                                                       WBf, qbuf, kbuf);
  edge_kernel<<<N_NODES / (4 * ITER), 256, 0, stream>>>(x, edge_attr, edge_index, batch,
                                                        bdk, ln_out_g, ln_out_b, qbuf,
                                                        kbuf, Wdkf, gsum);
  readout_kernel<<<NG, 64, 0, stream>>>(gsum, batch, Wout, bout, outp);
}